// Round 1
// baseline (125.598 us; speedup 1.0000x reference)
//
#include <hip/hip_runtime.h>
#include <stdint.h>

#define NB 4          // batches
#define M 5000        // boxes per batch
#define KOUT 2000     // output rois per batch
#define MP 5120       // padded M (multiple of 128)
#define NSORT 8192    // pow2 >= M for bitonic
#define NT 40         // tiles of 128 over MP
#define NTP 820       // NT*(NT+1)/2 upper-tri tile pairs
#define PAIR_CAP 8192 // per-batch suppression-pair capacity (~50x expected)

// ---------------- K1: per-batch stable descending sort by score ----------------
__global__ __launch_bounds__(1024) void k_sort(
    const float* __restrict__ boxes, const float* __restrict__ scores,
    float* __restrict__ sx1, float* __restrict__ sy1,
    float* __restrict__ sx2, float* __restrict__ sy2,
    unsigned int* __restrict__ cnt)
{
    __shared__ unsigned long long key[NSORT];
    const int b = blockIdx.x;
    const int t = threadIdx.x;
    if (t == 0) cnt[b] = 0u;  // zero pair counter for K2

    for (int i = t; i < NSORT; i += 1024) {
        unsigned long long kk;
        if (i < M) {
            unsigned int sb = __float_as_uint(scores[b * M + i]);
            // descending score, ascending index tiebreak (stable argsort(-s))
            kk = (((unsigned long long)(0xFFFFFFFFu - sb)) << 32) | (unsigned long long)(unsigned int)i;
        } else {
            kk = 0xFFFFFFFFFFFFFFFFull;
        }
        key[i] = kk;
    }
    __syncthreads();

    for (int k = 2; k <= NSORT; k <<= 1) {
        for (int j = k >> 1; j > 0; j >>= 1) {
            for (int p = t; p < (NSORT / 2); p += 1024) {
                int i = ((p & ~(j - 1)) << 1) | (p & (j - 1));
                int l = i | j;
                bool up = ((i & k) == 0);
                unsigned long long a = key[i];
                unsigned long long c = key[l];
                if ((a > c) == up) { key[i] = c; key[l] = a; }
            }
            __syncthreads();
        }
    }

    // gather sorted boxes into SoA workspace (bit-exact copies)
    for (int r = t; r < MP; r += 1024) {
        float x1, y1, x2, y2;
        if (r < M) {
            int m = (int)(unsigned int)(key[r] & 0xFFFFFFFFull);
            const float* bp = boxes + ((size_t)(b * M + m)) * 4;
            x1 = bp[0]; y1 = bp[1]; x2 = bp[2]; y2 = bp[3];
        } else {
            // far-away sentinel: never overlaps a real box, no NaN/Inf
            x1 = 3.0e9f; y1 = 3.0e9f; x2 = 3.0e9f; y2 = 3.0e9f;
        }
        sx1[b * MP + r] = x1;
        sy1[b * MP + r] = y1;
        sx2[b * MP + r] = x2;
        sy2[b * MP + r] = y2;
    }
}

// ---------------- K2: sparse suppression-pair detection ----------------
__global__ __launch_bounds__(256) void k_pairs(
    const float* __restrict__ sx1, const float* __restrict__ sy1,
    const float* __restrict__ sx2, const float* __restrict__ sy2,
    unsigned int* __restrict__ cnt, unsigned int* __restrict__ pairs)
{
    __shared__ float ax1[128], ay1[128], ax2[128], ay2[128], aA[128];
    __shared__ float bx1[128], by1[128], bx2[128], by2[128], aB[128];

    const int bid = blockIdx.x;
    const int b = bid / NTP;
    int rem = bid - b * NTP;
    int ti = 0;
    while (rem >= NT - ti) { rem -= NT - ti; ++ti; }
    const int tj = ti + rem;

    const int t = threadIdx.x;
    if (t < 128) {
        int g = ti * 128 + t;
        float x1 = sx1[b * MP + g], y1 = sy1[b * MP + g];
        float x2 = sx2[b * MP + g], y2 = sy2[b * MP + g];
        ax1[t] = x1; ay1[t] = y1; ax2[t] = x2; ay2[t] = y2;
        aA[t] = __fmul_rn(__fadd_rn(__fsub_rn(x2, x1), 1.0f),
                          __fadd_rn(__fsub_rn(y2, y1), 1.0f));
    } else {
        int tt = t - 128;
        int g = tj * 128 + tt;
        float x1 = sx1[b * MP + g], y1 = sy1[b * MP + g];
        float x2 = sx2[b * MP + g], y2 = sy2[b * MP + g];
        bx1[tt] = x1; by1[tt] = y1; bx2[tt] = x2; by2[tt] = y2;
        aB[tt] = __fmul_rn(__fadd_rn(__fsub_rn(x2, x1), 1.0f),
                           __fadd_rn(__fsub_rn(y2, y1), 1.0f));
    }
    __syncthreads();

    const int jj = t & 127;
    const int gj = tj * 128 + jj;
    if (gj >= M) return;  // no more barriers below
    const float qx1 = bx1[jj], qy1 = by1[jj], qx2 = bx2[jj], qy2 = by2[jj], qa = aB[jj];

    for (int ii = (t >> 7); ii < 128; ii += 2) {
        int gi = ti * 128 + ii;
        if (gi >= gj) continue;
        float xx1 = fmaxf(ax1[ii], qx1);
        float yy1 = fmaxf(ay1[ii], qy1);
        float xx2 = fminf(ax2[ii], qx2);
        float yy2 = fminf(ay2[ii], qy2);
        float w = __fadd_rn(__fsub_rn(xx2, xx1), 1.0f);
        float h = __fadd_rn(__fsub_rn(yy2, yy1), 1.0f);
        if (w > 0.0f && h > 0.0f) {
            float inter = __fmul_rn(w, h);
            float uni = __fsub_rn(__fadd_rn(aA[ii], qa), inter);
            float iou = __fdiv_rn(inter, uni);
            if (iou > 0.7f) {
                unsigned int pos = atomicAdd(&cnt[b], 1u);
                if (pos < PAIR_CAP)
                    pairs[b * PAIR_CAP + pos] = ((unsigned int)gi << 13) | (unsigned int)gj;
            }
        }
    }
}

// ---------------- K3: sort pairs, greedy scan, emit output ----------------
__global__ __launch_bounds__(1024) void k_scan(
    const float* __restrict__ sx1, const float* __restrict__ sy1,
    const float* __restrict__ sx2, const float* __restrict__ sy2,
    const unsigned int* __restrict__ cnt, const unsigned int* __restrict__ pairs,
    float* __restrict__ out)
{
    __shared__ unsigned int pk[PAIR_CAP];
    __shared__ unsigned char keep[MP];
    __shared__ int psum[1024];

    const int b = blockIdx.x;
    const int t = threadIdx.x;
    int n = (int)cnt[b];
    if (n > PAIR_CAP) n = PAIR_CAP;

    int P = 2;
    while (P < n) P <<= 1;

    for (int i = t; i < P; i += 1024)
        pk[i] = (i < n) ? pairs[b * PAIR_CAP + i] : 0xFFFFFFFFu;
    for (int i = t; i < MP; i += 1024)
        keep[i] = (i < M) ? (unsigned char)1 : (unsigned char)0;
    __syncthreads();

    if (n > 0) {
        // bitonic sort P u32 keys ascending (sorted by i, then j)
        for (int k = 2; k <= P; k <<= 1) {
            for (int j = k >> 1; j > 0; j >>= 1) {
                for (int p = t; p < (P >> 1); p += 1024) {
                    int i = ((p & ~(j - 1)) << 1) | (p & (j - 1));
                    int l = i | j;
                    bool up = ((i & k) == 0);
                    unsigned int a = pk[i], c = pk[l];
                    if ((a > c) == up) { pk[i] = c; pk[l] = a; }
                }
                __syncthreads();
            }
        }
        // exact greedy scan — pairs are sorted by suppressor index i
        if (t == 0) {
            for (int p = 0; p < n; ++p) {
                unsigned int v = pk[p];
                int i = (int)(v >> 13);
                int j = (int)(v & 8191u);
                if (keep[i]) keep[j] = 0;
            }
        }
        __syncthreads();
    }

    // block-wide prefix sum of keep[], 5 elems/thread
    const int base = t * 5;
    int s = 0;
    #pragma unroll
    for (int q = 0; q < 5; ++q) s += (int)keep[base + q];
    psum[t] = s;
    __syncthreads();
    for (int off = 1; off < 1024; off <<= 1) {
        int v = psum[t];
        int add = (t >= off) ? psum[t - off] : 0;
        __syncthreads();
        psum[t] = v + add;
        __syncthreads();
    }
    const int excl = psum[t] - s;
    const int total = psum[1023];

    // scatter kept rows
    int pos = excl;
    #pragma unroll
    for (int q = 0; q < 5; ++q) {
        int r = base + q;
        int kp = (int)keep[r];
        if (r < M && kp && pos < KOUT) {
            float* o = out + ((size_t)(b * KOUT + pos)) * 5;
            o[0] = (float)b;
            o[1] = sx1[b * MP + r];
            o[2] = sy1[b * MP + r];
            o[3] = sx2[b * MP + r];
            o[4] = sy2[b * MP + r];
        }
        pos += kp;
    }

    // zero rows [kept, KOUT)
    int kc = total; if (kc > KOUT) kc = KOUT;
    for (int e = kc * 5 + t; e < KOUT * 5; e += 1024)
        out[(size_t)b * KOUT * 5 + e] = 0.0f;

    // scalar losses
    if (b == 0 && t == 0) {
        out[(size_t)NB * KOUT * 5 + 0] = 0.0f;
        out[(size_t)NB * KOUT * 5 + 1] = 0.0f;
    }
}

extern "C" void kernel_launch(void* const* d_in, const int* in_sizes, int n_in,
                              void* d_out, int out_size, void* d_ws, size_t ws_size,
                              hipStream_t stream) {
    (void)in_sizes; (void)n_in; (void)out_size; (void)ws_size;
    const float* boxes  = (const float*)d_in[0];
    const float* scores = (const float*)d_in[1];
    float* out = (float*)d_out;

    // ws layout: 4 SoA coord arrays [NB*MP] + cnt[16] + pairs[NB*PAIR_CAP]  (~450 KB)
    float* sx1 = (float*)d_ws;
    float* sy1 = sx1 + NB * MP;
    float* sx2 = sy1 + NB * MP;
    float* sy2 = sx2 + NB * MP;
    unsigned int* cnt   = (unsigned int*)(sy2 + NB * MP);
    unsigned int* pairs = cnt + 16;

    hipLaunchKernelGGL(k_sort,  dim3(NB),       dim3(1024), 0, stream,
                       boxes, scores, sx1, sy1, sx2, sy2, cnt);
    hipLaunchKernelGGL(k_pairs, dim3(NB * NTP), dim3(256),  0, stream,
                       sx1, sy1, sx2, sy2, cnt, pairs);
    hipLaunchKernelGGL(k_scan,  dim3(NB),       dim3(1024), 0, stream,
                       sx1, sy1, sx2, sy2, cnt, pairs, out);
}

// Round 2
// 79.576 us; speedup vs baseline: 1.5783x; 1.5783x over previous
//
#include <hip/hip_runtime.h>
#include <stdint.h>

#define NB 4          // batches
#define M 5000        // boxes per batch
#define KOUT 2000     // output rois per batch
#define MP 5120       // padded M (multiple of 128)
#define NT 40         // tiles of 128 over MP
#define NTP 820       // NT*(NT+1)/2 upper-tri tile pairs
#define PAIR_CAP 8192 // per-batch suppression-pair capacity (~50x expected)

#define IPB 64        // i's ranked per block
#define NBI 79        // ceil(M/IPB)
#define JQ 1250       // j-range per quarter (M/4)

// ---------------- K1: full-chip rank sort (stable argsort(-scores)) ----------------
// key[i] = (~score_bits << 32) | i  (u64, distinct)  — rank = #{j: key[j] < key[i]}
__global__ __launch_bounds__(256) void k_rank(
    const float* __restrict__ boxes, const float* __restrict__ scores,
    float* __restrict__ sx1, float* __restrict__ sy1,
    float* __restrict__ sx2, float* __restrict__ sy2,
    unsigned int* __restrict__ cnt)
{
    __shared__ unsigned long long skey[M];
    __shared__ int part[256];

    const int bid = blockIdx.x;
    const int b = bid / NBI;
    const int ic = bid - b * NBI;
    const int t = threadIdx.x;

    // stage all keys of this batch
    for (int j = t; j < M; j += 256) {
        unsigned int sb = __float_as_uint(scores[b * M + j]);
        skey[j] = (((unsigned long long)(~sb)) << 32) | (unsigned long long)(unsigned int)j;
    }
    __syncthreads();

    const int i = ic * IPB + (t & 63);
    const int q = t >> 6;
    const unsigned long long ki = (i < M) ? skey[i] : 0xFFFFFFFFFFFFFFFFull;

    int r = 0;
    const int j0 = q * JQ;
    #pragma unroll 8
    for (int j = j0; j < j0 + JQ; ++j)
        r += (skey[j] < ki) ? 1 : 0;

    part[t] = r;
    __syncthreads();

    if (t < 64) {
        int rank = part[t] + part[t + 64] + part[t + 128] + part[t + 192];
        if (i < M) {
            float4 bx = ((const float4*)boxes)[b * M + i];
            sx1[b * MP + rank] = bx.x;
            sy1[b * MP + rank] = bx.y;
            sx2[b * MP + rank] = bx.z;
            sy2[b * MP + rank] = bx.w;
        }
    }

    if (ic == 0) {
        if (t < (MP - M)) {
            // far-away sentinel rows: never overlap a real box, no NaN/Inf
            int rr = M + t;
            sx1[b * MP + rr] = 3.0e9f;
            sy1[b * MP + rr] = 3.0e9f;
            sx2[b * MP + rr] = 3.0e9f;
            sy2[b * MP + rr] = 3.0e9f;
        }
        if (t == 0) cnt[b] = 0u;  // zero pair counter for K2
    }
}

// ---------------- K2: sparse suppression-pair detection ----------------
__global__ __launch_bounds__(256) void k_pairs(
    const float* __restrict__ sx1, const float* __restrict__ sy1,
    const float* __restrict__ sx2, const float* __restrict__ sy2,
    unsigned int* __restrict__ cnt, unsigned int* __restrict__ pairs)
{
    __shared__ float ax1[128], ay1[128], ax2[128], ay2[128], aA[128];
    __shared__ float bx1[128], by1[128], bx2[128], by2[128], aB[128];

    const int bid = blockIdx.x;
    const int b = bid / NTP;
    int rem = bid - b * NTP;
    int ti = 0;
    while (rem >= NT - ti) { rem -= NT - ti; ++ti; }
    const int tj = ti + rem;

    const int t = threadIdx.x;
    if (t < 128) {
        int g = ti * 128 + t;
        float x1 = sx1[b * MP + g], y1 = sy1[b * MP + g];
        float x2 = sx2[b * MP + g], y2 = sy2[b * MP + g];
        ax1[t] = x1; ay1[t] = y1; ax2[t] = x2; ay2[t] = y2;
        aA[t] = __fmul_rn(__fadd_rn(__fsub_rn(x2, x1), 1.0f),
                          __fadd_rn(__fsub_rn(y2, y1), 1.0f));
    } else {
        int tt = t - 128;
        int g = tj * 128 + tt;
        float x1 = sx1[b * MP + g], y1 = sy1[b * MP + g];
        float x2 = sx2[b * MP + g], y2 = sy2[b * MP + g];
        bx1[tt] = x1; by1[tt] = y1; bx2[tt] = x2; by2[tt] = y2;
        aB[tt] = __fmul_rn(__fadd_rn(__fsub_rn(x2, x1), 1.0f),
                           __fadd_rn(__fsub_rn(y2, y1), 1.0f));
    }
    __syncthreads();

    const int jj = t & 127;
    const int gj = tj * 128 + jj;
    if (gj >= M) return;  // no more barriers below
    const float qx1 = bx1[jj], qy1 = by1[jj], qx2 = bx2[jj], qy2 = by2[jj], qa = aB[jj];

    for (int ii = (t >> 7); ii < 128; ii += 2) {
        int gi = ti * 128 + ii;
        if (gi >= gj) continue;
        float xx1 = fmaxf(ax1[ii], qx1);
        float yy1 = fmaxf(ay1[ii], qy1);
        float xx2 = fminf(ax2[ii], qx2);
        float yy2 = fminf(ay2[ii], qy2);
        float w = __fadd_rn(__fsub_rn(xx2, xx1), 1.0f);
        float h = __fadd_rn(__fsub_rn(yy2, yy1), 1.0f);
        if (w > 0.0f && h > 0.0f) {
            float inter = __fmul_rn(w, h);
            float uni = __fsub_rn(__fadd_rn(aA[ii], qa), inter);
            float iou = __fdiv_rn(inter, uni);
            if (iou > 0.7f) {
                unsigned int pos = atomicAdd(&cnt[b], 1u);
                if (pos < PAIR_CAP)
                    pairs[b * PAIR_CAP + pos] = ((unsigned int)gi << 13) | (unsigned int)gj;
            }
        }
    }
}

// ---------------- K3: sort pairs, greedy scan, emit output ----------------
__global__ __launch_bounds__(1024) void k_scan(
    const float* __restrict__ sx1, const float* __restrict__ sy1,
    const float* __restrict__ sx2, const float* __restrict__ sy2,
    const unsigned int* __restrict__ cnt, const unsigned int* __restrict__ pairs,
    float* __restrict__ out)
{
    __shared__ unsigned int pk[PAIR_CAP];
    __shared__ unsigned char keep[MP];
    __shared__ int psum[1024];

    const int b = blockIdx.x;
    const int t = threadIdx.x;
    int n = (int)cnt[b];
    if (n > PAIR_CAP) n = PAIR_CAP;

    int P = 2;
    while (P < n) P <<= 1;

    for (int i = t; i < P; i += 1024)
        pk[i] = (i < n) ? pairs[b * PAIR_CAP + i] : 0xFFFFFFFFu;
    for (int i = t; i < MP; i += 1024)
        keep[i] = (i < M) ? (unsigned char)1 : (unsigned char)0;
    __syncthreads();

    if (n > 0) {
        // bitonic sort P u32 keys ascending (by suppressor i, then j)
        for (int k = 2; k <= P; k <<= 1) {
            for (int j = k >> 1; j > 0; j >>= 1) {
                for (int p = t; p < (P >> 1); p += 1024) {
                    int i = ((p & ~(j - 1)) << 1) | (p & (j - 1));
                    int l = i | j;
                    bool up = ((i & k) == 0);
                    unsigned int a = pk[i], c = pk[l];
                    if ((a > c) == up) { pk[i] = c; pk[l] = a; }
                }
                __syncthreads();
            }
        }
        // exact greedy scan — pairs sorted by suppressor index i
        if (t == 0) {
            for (int p = 0; p < n; ++p) {
                unsigned int v = pk[p];
                int i = (int)(v >> 13);
                int j = (int)(v & 8191u);
                if (keep[i]) keep[j] = 0;
            }
        }
        __syncthreads();
    }

    // block-wide prefix sum of keep[], 5 elems/thread
    const int base = t * 5;
    int s = 0;
    #pragma unroll
    for (int q = 0; q < 5; ++q) s += (int)keep[base + q];
    psum[t] = s;
    __syncthreads();
    for (int off = 1; off < 1024; off <<= 1) {
        int v = psum[t];
        int add = (t >= off) ? psum[t - off] : 0;
        __syncthreads();
        psum[t] = v + add;
        __syncthreads();
    }
    const int excl = psum[t] - s;
    const int total = psum[1023];

    // scatter kept rows
    int pos = excl;
    #pragma unroll
    for (int q = 0; q < 5; ++q) {
        int r = base + q;
        int kp = (int)keep[r];
        if (r < M && kp && pos < KOUT) {
            float* o = out + ((size_t)(b * KOUT + pos)) * 5;
            o[0] = (float)b;
            o[1] = sx1[b * MP + r];
            o[2] = sy1[b * MP + r];
            o[3] = sx2[b * MP + r];
            o[4] = sy2[b * MP + r];
        }
        pos += kp;
    }

    // zero rows [kept, KOUT)
    int kc = total; if (kc > KOUT) kc = KOUT;
    for (int e = kc * 5 + t; e < KOUT * 5; e += 1024)
        out[(size_t)b * KOUT * 5 + e] = 0.0f;

    // scalar losses
    if (b == 0 && t == 0) {
        out[(size_t)NB * KOUT * 5 + 0] = 0.0f;
        out[(size_t)NB * KOUT * 5 + 1] = 0.0f;
    }
}

extern "C" void kernel_launch(void* const* d_in, const int* in_sizes, int n_in,
                              void* d_out, int out_size, void* d_ws, size_t ws_size,
                              hipStream_t stream) {
    (void)in_sizes; (void)n_in; (void)out_size; (void)ws_size;
    const float* boxes  = (const float*)d_in[0];
    const float* scores = (const float*)d_in[1];
    float* out = (float*)d_out;

    // ws layout: 4 SoA coord arrays [NB*MP] + cnt[16] + pairs[NB*PAIR_CAP]  (~450 KB)
    float* sx1 = (float*)d_ws;
    float* sy1 = sx1 + NB * MP;
    float* sx2 = sy1 + NB * MP;
    float* sy2 = sx2 + NB * MP;
    unsigned int* cnt   = (unsigned int*)(sy2 + NB * MP);
    unsigned int* pairs = cnt + 16;

    hipLaunchKernelGGL(k_rank,  dim3(NB * NBI), dim3(256), 0, stream,
                       boxes, scores, sx1, sy1, sx2, sy2, cnt);
    hipLaunchKernelGGL(k_pairs, dim3(NB * NTP), dim3(256), 0, stream,
                       sx1, sy1, sx2, sy2, cnt, pairs);
    hipLaunchKernelGGL(k_scan,  dim3(NB),       dim3(1024), 0, stream,
                       sx1, sy1, sx2, sy2, cnt, pairs, out);
}

// Round 3
// 77.156 us; speedup vs baseline: 1.6278x; 1.0314x over previous
//
#include <hip/hip_runtime.h>
#include <stdint.h>

#define NB 4          // batches
#define M 5000        // boxes per batch
#define KOUT 2000     // output rois per batch
#define MP 5120       // padded M (multiple of 128)
#define NT 40         // tiles of 128 over MP
#define NTP 820       // NT*(NT+1)/2 upper-tri tile pairs
#define PAIR_CAP 8192 // per-batch pair capacity (global buffer)
#define SCAP 4096     // pair capacity staged in LDS for k_scan (n ~150 expected)

#define IPB 16        // i's ranked per block
#define NBI 313       // ceil(M/IPB)
#define MSS 5008      // padded score array (>= NBI*IPB = 5008)

// ---------------- K1: full-chip rank sort (stable argsort(-scores)) ----------------
// rank(i) = #{j<i: s_j >= s_i} + #{j>i: s_j > s_i}  == stable descending rank
__global__ __launch_bounds__(256) void k_rank(
    const float* __restrict__ boxes, const float* __restrict__ scores,
    float* __restrict__ sx1, float* __restrict__ sy1,
    float* __restrict__ sx2, float* __restrict__ sy2,
    unsigned int* __restrict__ cnt)
{
    __shared__ __align__(16) float ss[MSS];
    __shared__ int part[256];

    const int bid = blockIdx.x;
    const int b = bid / NBI;
    const int ic = bid - b * NBI;
    const int t = threadIdx.x;

    for (int j = t; j < MSS; j += 256)
        ss[j] = (j < M) ? scores[b * M + j] : 0.0f;
    __syncthreads();

    const int isub = t & 15;
    const int q = t >> 4;               // 16-way j-split
    const int i = ic * IPB + isub;      // i < MSS always
    const float si = ss[i];

    int r = 0;
    const float4* ss4 = (const float4*)ss;
    #pragma unroll 4
    for (int c = q; c < (M / 4); c += 16) {   // 4 q-groups/wave -> disjoint LDS bank quads
        float4 v = ss4[c];
        int j = 4 * c;
        r += (j + 0 < i) ? (v.x >= si) : (v.x > si);
        r += (j + 1 < i) ? (v.y >= si) : (v.y > si);
        r += (j + 2 < i) ? (v.z >= si) : (v.z > si);
        r += (j + 3 < i) ? (v.w >= si) : (v.w > si);
    }
    part[t] = r;
    __syncthreads();

    if (t < IPB) {
        const int ii = ic * IPB + t;
        if (ii < M) {
            int rank = 0;
            #pragma unroll
            for (int qq = 0; qq < 16; ++qq) rank += part[t + 16 * qq];
            float4 bx = ((const float4*)boxes)[b * M + ii];
            sx1[b * MP + rank] = bx.x;
            sy1[b * MP + rank] = bx.y;
            sx2[b * MP + rank] = bx.z;
            sy2[b * MP + rank] = bx.w;
        }
    }

    if (ic == 0) {
        if (t < (MP - M)) {
            // far-away sentinel rows: never overlap a real box, no NaN/Inf
            int rr = M + t;
            sx1[b * MP + rr] = 3.0e9f;
            sy1[b * MP + rr] = 3.0e9f;
            sx2[b * MP + rr] = 3.0e9f;
            sy2[b * MP + rr] = 3.0e9f;
        }
        if (t == 0) cnt[b] = 0u;  // zero pair counter for K2
    }
}

// ---------------- K2: sparse suppression-pair detection ----------------
__global__ __launch_bounds__(256) void k_pairs(
    const float* __restrict__ sx1, const float* __restrict__ sy1,
    const float* __restrict__ sx2, const float* __restrict__ sy2,
    unsigned int* __restrict__ cnt, unsigned int* __restrict__ pairs)
{
    __shared__ __align__(16) float4 abox[128];
    __shared__ float aA[128];
    __shared__ __align__(16) float4 bbox[128];
    __shared__ float aB[128];

    const int bid = blockIdx.x;
    const int b = bid / NTP;
    int rem = bid - b * NTP;
    int ti = 0;
    while (rem >= NT - ti) { rem -= NT - ti; ++ti; }
    const int tj = ti + rem;

    const int t = threadIdx.x;
    if (t < 128) {
        int g = ti * 128 + t;
        float x1 = sx1[b * MP + g], y1 = sy1[b * MP + g];
        float x2 = sx2[b * MP + g], y2 = sy2[b * MP + g];
        abox[t] = make_float4(x1, y1, x2, y2);
        aA[t] = __fmul_rn(__fadd_rn(__fsub_rn(x2, x1), 1.0f),
                          __fadd_rn(__fsub_rn(y2, y1), 1.0f));
    } else {
        int tt = t - 128;
        int g = tj * 128 + tt;
        float x1 = sx1[b * MP + g], y1 = sy1[b * MP + g];
        float x2 = sx2[b * MP + g], y2 = sy2[b * MP + g];
        bbox[tt] = make_float4(x1, y1, x2, y2);
        aB[tt] = __fmul_rn(__fadd_rn(__fsub_rn(x2, x1), 1.0f),
                           __fadd_rn(__fsub_rn(y2, y1), 1.0f));
    }
    __syncthreads();

    const int jj = t & 127;
    const int gj = tj * 128 + jj;
    if (gj >= M) return;  // no more barriers below
    const float4 qb = bbox[jj];
    const float qa = aB[jj];

    for (int ii = (t >> 7); ii < 128; ii += 2) {
        int gi = ti * 128 + ii;
        if (gi >= gj) continue;
        float4 av = abox[ii];               // one b128 broadcast
        float xx1 = fmaxf(av.x, qb.x);
        float yy1 = fmaxf(av.y, qb.y);
        float xx2 = fminf(av.z, qb.z);
        float yy2 = fminf(av.w, qb.w);
        float w = __fadd_rn(__fsub_rn(xx2, xx1), 1.0f);
        float h = __fadd_rn(__fsub_rn(yy2, yy1), 1.0f);
        if (w > 0.0f && h > 0.0f) {
            float inter = __fmul_rn(w, h);
            float uni = __fsub_rn(__fadd_rn(aA[ii], qa), inter);
            float iou = __fdiv_rn(inter, uni);
            if (iou > 0.7f) {
                unsigned int pos = atomicAdd(&cnt[b], 1u);
                if (pos < PAIR_CAP)
                    pairs[b * PAIR_CAP + pos] = ((unsigned int)gi << 13) | (unsigned int)gj;
            }
        }
    }
}

// ---------------- K3: rank-sort pairs, greedy scan, emit output ----------------
__global__ __launch_bounds__(1024) void k_scan(
    const float* __restrict__ sx1, const float* __restrict__ sy1,
    const float* __restrict__ sx2, const float* __restrict__ sy2,
    const unsigned int* __restrict__ cnt, const unsigned int* __restrict__ pairs,
    float* __restrict__ out)
{
    __shared__ unsigned int pk[SCAP];
    __shared__ unsigned int srt[SCAP];
    __shared__ unsigned char keep[MP];
    __shared__ int wsum[16];
    __shared__ int woff[16];

    const int b = blockIdx.x;
    const int t = threadIdx.x;
    int n = (int)cnt[b];
    if (n > SCAP) n = SCAP;

    for (int e = t; e < n; e += 1024)
        pk[e] = pairs[b * PAIR_CAP + e];
    for (int e = t; e < MP; e += 1024)
        keep[e] = (e < M) ? (unsigned char)1 : (unsigned char)0;
    __syncthreads();

    // rank sort (keys distinct by construction): 1 barrier total
    for (int e = t; e < n; e += 1024) {
        unsigned int v = pk[e];
        int rk = 0;
        for (int f = 0; f < n; ++f) rk += (pk[f] < v) ? 1 : 0;
        srt[rk] = v;
    }
    __syncthreads();

    // exact greedy scan — pairs sorted by suppressor index i
    if (t == 0) {
        for (int p = 0; p < n; ++p) {
            unsigned int v = srt[p];
            int i = (int)(v >> 13);
            int j = (int)(v & 8191u);
            if (keep[i]) keep[j] = 0;
        }
    }
    __syncthreads();

    // prefix sum of keep[]: per-thread sum(5) -> wave shfl-scan -> 16-wave combine
    const int base = t * 5;
    int s = 0;
    #pragma unroll
    for (int qq = 0; qq < 5; ++qq) s += (int)keep[base + qq];

    const int lane = t & 63;
    const int w = t >> 6;
    int sc = s;
    #pragma unroll
    for (int d = 1; d < 64; d <<= 1) {
        int v = __shfl_up(sc, d, 64);
        if (lane >= d) sc += v;
    }
    if (lane == 63) wsum[w] = sc;
    __syncthreads();
    if (t == 0) {
        int acc = 0;
        #pragma unroll
        for (int ww = 0; ww < 16; ++ww) { woff[ww] = acc; acc += wsum[ww]; }
    }
    __syncthreads();
    const int excl = woff[w] + (sc - s);
    const int total = woff[15] + wsum[15];

    // scatter kept rows
    int pos = excl;
    #pragma unroll
    for (int qq = 0; qq < 5; ++qq) {
        int r = base + qq;
        int kp = (int)keep[r];
        if (kp && pos < KOUT) {
            float* o = out + ((size_t)(b * KOUT + pos)) * 5;
            o[0] = (float)b;
            o[1] = sx1[b * MP + r];
            o[2] = sy1[b * MP + r];
            o[3] = sx2[b * MP + r];
            o[4] = sy2[b * MP + r];
        }
        pos += kp;
    }

    // zero rows [kept, KOUT)
    int kc = total; if (kc > KOUT) kc = KOUT;
    for (int e = kc * 5 + t; e < KOUT * 5; e += 1024)
        out[(size_t)b * KOUT * 5 + e] = 0.0f;

    // scalar losses
    if (b == 0 && t == 0) {
        out[(size_t)NB * KOUT * 5 + 0] = 0.0f;
        out[(size_t)NB * KOUT * 5 + 1] = 0.0f;
    }
}

extern "C" void kernel_launch(void* const* d_in, const int* in_sizes, int n_in,
                              void* d_out, int out_size, void* d_ws, size_t ws_size,
                              hipStream_t stream) {
    (void)in_sizes; (void)n_in; (void)out_size; (void)ws_size;
    const float* boxes  = (const float*)d_in[0];
    const float* scores = (const float*)d_in[1];
    float* out = (float*)d_out;

    // ws layout: 4 SoA coord arrays [NB*MP] + cnt[16] + pairs[NB*PAIR_CAP]  (~450 KB)
    float* sx1 = (float*)d_ws;
    float* sy1 = sx1 + NB * MP;
    float* sx2 = sy1 + NB * MP;
    float* sy2 = sx2 + NB * MP;
    unsigned int* cnt   = (unsigned int*)(sy2 + NB * MP);
    unsigned int* pairs = cnt + 16;

    hipLaunchKernelGGL(k_rank,  dim3(NB * NBI), dim3(256),  0, stream,
                       boxes, scores, sx1, sy1, sx2, sy2, cnt);
    hipLaunchKernelGGL(k_pairs, dim3(NB * NTP), dim3(256),  0, stream,
                       sx1, sy1, sx2, sy2, cnt, pairs);
    hipLaunchKernelGGL(k_scan,  dim3(NB),       dim3(1024), 0, stream,
                       sx1, sy1, sx2, sy2, cnt, pairs, out);
}

// Round 4
// 74.247 us; speedup vs baseline: 1.6916x; 1.0392x over previous
//
#include <hip/hip_runtime.h>
#include <stdint.h>

#define NB 4          // batches
#define M 5000        // boxes per batch
#define KOUT 2000     // output rois per batch
#define MP 5120       // padded M (multiple of 128)
#define NT 40         // tiles of 128 over MP
#define NTP 820       // NT*(NT+1)/2 upper-tri tile pairs
#define PAIR_CAP 8192 // per-batch pair capacity (global buffer)
#define SCAP 4096     // pair capacity staged in LDS for k_scan (n ~500 expected)

#define IPB 16        // i's ranked per block
#define NBI 313       // ceil(M/IPB)
#define MSS 5008      // padded score array (>= NBI*IPB = 5008)

// ---------------- K1: full-chip rank sort (stable argsort(-scores)) ----------------
// rank(i) = #{j<i: s_j >= s_i} + #{j>i: s_j > s_i}  == stable descending rank
__global__ __launch_bounds__(256) void k_rank(
    const float* __restrict__ boxes, const float* __restrict__ scores,
    float* __restrict__ sx1, float* __restrict__ sy1,
    float* __restrict__ sx2, float* __restrict__ sy2,
    unsigned int* __restrict__ cnt)
{
    __shared__ __align__(16) float ss[MSS];
    __shared__ int part[256];

    const int bid = blockIdx.x;
    const int b = bid / NBI;
    const int ic = bid - b * NBI;
    const int t = threadIdx.x;

    for (int j = t; j < MSS; j += 256)
        ss[j] = (j < M) ? scores[b * M + j] : 0.0f;
    __syncthreads();

    const int isub = t & 15;
    const int q = t >> 4;               // 16-way j-split
    const int i = ic * IPB + isub;      // i < MSS always
    const float si = ss[i];

    int r = 0;
    const float4* ss4 = (const float4*)ss;
    #pragma unroll 4
    for (int c = q; c < (M / 4); c += 16) {   // 4 q-groups/wave -> disjoint LDS bank quads
        float4 v = ss4[c];
        int j = 4 * c;
        r += (j + 0 < i) ? (v.x >= si) : (v.x > si);
        r += (j + 1 < i) ? (v.y >= si) : (v.y > si);
        r += (j + 2 < i) ? (v.z >= si) : (v.z > si);
        r += (j + 3 < i) ? (v.w >= si) : (v.w > si);
    }
    part[t] = r;
    __syncthreads();

    if (t < IPB) {
        const int ii = ic * IPB + t;
        if (ii < M) {
            int rank = 0;
            #pragma unroll
            for (int qq = 0; qq < 16; ++qq) rank += part[t + 16 * qq];
            float4 bx = ((const float4*)boxes)[b * M + ii];
            sx1[b * MP + rank] = bx.x;
            sy1[b * MP + rank] = bx.y;
            sx2[b * MP + rank] = bx.z;
            sy2[b * MP + rank] = bx.w;
        }
    }

    if (ic == 0) {
        if (t < (MP - M)) {
            // far-away sentinel rows: never overlap a real box, no NaN/Inf
            int rr = M + t;
            sx1[b * MP + rr] = 3.0e9f;
            sy1[b * MP + rr] = 3.0e9f;
            sx2[b * MP + rr] = 3.0e9f;
            sy2[b * MP + rr] = 3.0e9f;
        }
        if (t == 0) cnt[b] = 0u;  // zero pair counter for K2
    }
}

// ---------------- K2: sparse suppression-pair detection ----------------
__global__ __launch_bounds__(256) void k_pairs(
    const float* __restrict__ sx1, const float* __restrict__ sy1,
    const float* __restrict__ sx2, const float* __restrict__ sy2,
    unsigned int* __restrict__ cnt, unsigned int* __restrict__ pairs)
{
    __shared__ __align__(16) float4 abox[128];
    __shared__ float aA[128];
    __shared__ __align__(16) float4 bbox[128];
    __shared__ float aB[128];

    const int bid = blockIdx.x;
    const int b = bid / NTP;
    int rem = bid - b * NTP;
    int ti = 0;
    while (rem >= NT - ti) { rem -= NT - ti; ++ti; }
    const int tj = ti + rem;

    const int t = threadIdx.x;
    if (t < 128) {
        int g = ti * 128 + t;
        float x1 = sx1[b * MP + g], y1 = sy1[b * MP + g];
        float x2 = sx2[b * MP + g], y2 = sy2[b * MP + g];
        abox[t] = make_float4(x1, y1, x2, y2);
        aA[t] = __fmul_rn(__fadd_rn(__fsub_rn(x2, x1), 1.0f),
                          __fadd_rn(__fsub_rn(y2, y1), 1.0f));
    } else {
        int tt = t - 128;
        int g = tj * 128 + tt;
        float x1 = sx1[b * MP + g], y1 = sy1[b * MP + g];
        float x2 = sx2[b * MP + g], y2 = sy2[b * MP + g];
        bbox[tt] = make_float4(x1, y1, x2, y2);
        aB[tt] = __fmul_rn(__fadd_rn(__fsub_rn(x2, x1), 1.0f),
                           __fadd_rn(__fsub_rn(y2, y1), 1.0f));
    }
    __syncthreads();

    const int jj = t & 127;
    const int gj = tj * 128 + jj;
    if (gj >= M) return;  // no more barriers below
    const float4 qb = bbox[jj];
    const float qa = aB[jj];

    for (int ii = (t >> 7); ii < 128; ii += 2) {
        int gi = ti * 128 + ii;
        if (gi >= gj) continue;
        float4 av = abox[ii];               // one b128 broadcast
        float xx1 = fmaxf(av.x, qb.x);
        float yy1 = fmaxf(av.y, qb.y);
        float xx2 = fminf(av.z, qb.z);
        float yy2 = fminf(av.w, qb.w);
        float w = __fadd_rn(__fsub_rn(xx2, xx1), 1.0f);
        float h = __fadd_rn(__fsub_rn(yy2, yy1), 1.0f);
        if (w > 0.0f && h > 0.0f) {
            float inter = __fmul_rn(w, h);
            float uni = __fsub_rn(__fadd_rn(aA[ii], qa), inter);
            float iou = __fdiv_rn(inter, uni);
            if (iou > 0.7f) {
                unsigned int pos = atomicAdd(&cnt[b], 1u);
                if (pos < PAIR_CAP)
                    pairs[b * PAIR_CAP + pos] = ((unsigned int)gi << 13) | (unsigned int)gj;
            }
        }
    }
}

// ---------------- K3: Jacobi fixpoint of greedy suppression, emit output ----------------
// sup[j] = OR over pairs (i,j) of !sup[i]; DAG (i<j) => unique fixpoint, exact.
__global__ __launch_bounds__(1024) void k_scan(
    const float* __restrict__ sx1, const float* __restrict__ sy1,
    const float* __restrict__ sx2, const float* __restrict__ sy2,
    const unsigned int* __restrict__ cnt, const unsigned int* __restrict__ pairs,
    float* __restrict__ out)
{
    __shared__ unsigned int pk[SCAP];
    __shared__ unsigned char sup[MP];
    __shared__ unsigned char nsup[MP];
    __shared__ int chflag;
    __shared__ int wsum[16];
    __shared__ int woff[16];

    const int b = blockIdx.x;
    const int t = threadIdx.x;
    int n = (int)cnt[b];
    if (n > SCAP) n = SCAP;

    for (int e = t; e < n; e += 1024)
        pk[e] = pairs[b * PAIR_CAP + e];
    for (int e = t; e < MP; e += 1024)
        sup[e] = 0;
    __syncthreads();

    // Jacobi rounds; node at dependency-depth d is correct&stable after round d;
    // a no-change round == fixpoint (unique on DAG). Cap n+2 guarantees exit.
    for (int round = 0; round < n + 2; ++round) {
        for (int e = t; e < MP; e += 1024) nsup[e] = 0;
        if (t == 0) chflag = 0;
        __syncthreads();                       // clears visible
        for (int e = t; e < n; e += 1024) {
            unsigned int v = pk[e];
            int i = (int)(v >> 13);
            int j = (int)(v & 8191u);
            if (!sup[i]) nsup[j] = 1;          // benign race: all write 1
        }
        __syncthreads();                       // nsup complete
        int ch = 0;
        for (int e = t; e < MP; e += 1024) {
            unsigned char nv = nsup[e];
            if (nv != sup[e]) { sup[e] = nv; ch = 1; }
        }
        if (ch) chflag = 1;
        __syncthreads();                       // copies + flag visible
        int done = (chflag == 0);
        __syncthreads();                       // all read flag before next clear
        if (done) break;
    }

    // prefix sum of keep = !sup: per-thread sum(5) -> wave shfl-scan -> 16-wave combine
    const int base = t * 5;
    int kp[5];
    int s = 0;
    #pragma unroll
    for (int qq = 0; qq < 5; ++qq) {
        int r = base + qq;
        kp[qq] = (r < M) ? (sup[r] ? 0 : 1) : 0;
        s += kp[qq];
    }

    const int lane = t & 63;
    const int w = t >> 6;
    int sc = s;
    #pragma unroll
    for (int d = 1; d < 64; d <<= 1) {
        int v = __shfl_up(sc, d, 64);
        if (lane >= d) sc += v;
    }
    if (lane == 63) wsum[w] = sc;
    __syncthreads();
    if (t == 0) {
        int acc = 0;
        #pragma unroll
        for (int ww = 0; ww < 16; ++ww) { woff[ww] = acc; acc += wsum[ww]; }
    }
    __syncthreads();
    const int excl = woff[w] + (sc - s);
    const int total = woff[15] + wsum[15];

    // scatter kept rows
    int pos = excl;
    #pragma unroll
    for (int qq = 0; qq < 5; ++qq) {
        int r = base + qq;
        if (kp[qq] && pos < KOUT) {
            float* o = out + ((size_t)(b * KOUT + pos)) * 5;
            o[0] = (float)b;
            o[1] = sx1[b * MP + r];
            o[2] = sy1[b * MP + r];
            o[3] = sx2[b * MP + r];
            o[4] = sy2[b * MP + r];
        }
        pos += kp[qq];
    }

    // zero rows [kept, KOUT)
    int kc = total; if (kc > KOUT) kc = KOUT;
    for (int e = kc * 5 + t; e < KOUT * 5; e += 1024)
        out[(size_t)b * KOUT * 5 + e] = 0.0f;

    // scalar losses
    if (b == 0 && t == 0) {
        out[(size_t)NB * KOUT * 5 + 0] = 0.0f;
        out[(size_t)NB * KOUT * 5 + 1] = 0.0f;
    }
}

extern "C" void kernel_launch(void* const* d_in, const int* in_sizes, int n_in,
                              void* d_out, int out_size, void* d_ws, size_t ws_size,
                              hipStream_t stream) {
    (void)in_sizes; (void)n_in; (void)out_size; (void)ws_size;
    const float* boxes  = (const float*)d_in[0];
    const float* scores = (const float*)d_in[1];
    float* out = (float*)d_out;

    // ws layout: 4 SoA coord arrays [NB*MP] + cnt[16] + pairs[NB*PAIR_CAP]  (~450 KB)
    float* sx1 = (float*)d_ws;
    float* sy1 = sx1 + NB * MP;
    float* sx2 = sy1 + NB * MP;
    float* sy2 = sx2 + NB * MP;
    unsigned int* cnt   = (unsigned int*)(sy2 + NB * MP);
    unsigned int* pairs = cnt + 16;

    hipLaunchKernelGGL(k_rank,  dim3(NB * NBI), dim3(256),  0, stream,
                       boxes, scores, sx1, sy1, sx2, sy2, cnt);
    hipLaunchKernelGGL(k_pairs, dim3(NB * NTP), dim3(256),  0, stream,
                       sx1, sy1, sx2, sy2, cnt, pairs);
    hipLaunchKernelGGL(k_scan,  dim3(NB),       dim3(1024), 0, stream,
                       sx1, sy1, sx2, sy2, cnt, pairs, out);
}